// Round 5
// baseline (151.467 us; speedup 1.0000x reference)
//
#include <hip/hip_runtime.h>
#include <hip/hip_bf16.h>

typedef unsigned short u16;
typedef unsigned int u32;
typedef __bf16 bf16;
typedef __attribute__((ext_vector_type(8))) __bf16 bf16x8;
typedef __attribute__((ext_vector_type(4))) __bf16 bf16x4;
typedef __attribute__((ext_vector_type(16))) float f32x16;

#define MFMA32(A,B,C) __builtin_amdgcn_mfma_f32_32x32x16_bf16(A,B,C,0,0,0)

constexpr int NTOK = 49;
constexpr int CH   = 128;
// softmax scale folded into exp2: SCALE * log2(e)
constexpr float CEXP = 0.17677669529663687f * 1.4426950408889634f;

__device__ __forceinline__ f32x16 zero16() {
    f32x16 z = {0.f,0.f,0.f,0.f,0.f,0.f,0.f,0.f,0.f,0.f,0.f,0.f,0.f,0.f,0.f,0.f};
    return z;
}

__device__ __forceinline__ u32 pkbf(float a, float b) {
    u16 lo = __builtin_bit_cast(u16, (bf16)a);
    u16 hi = __builtin_bit_cast(u16, (bf16)b);
    return (u32)lo | ((u32)hi << 16);
}

// Cross-half exchange: D-layout (row=(reg&3)+8*(reg>>2)+4*hd) -> A/B-frag layout
// (k = c2*16 + hd*8 + j). For frag chunk c2: lo = pk[2*c2][j] (m=2c2), hi = pk[2c2+1][j].
// u32[j]   (k-pair from half 0 lanes): hd==0 -> own lo ; hd==1 -> partner's hi
// u32[2+j] (k-pair from half 1 lanes): hd==0 -> partner's lo ; hd==1 -> own hi
__device__ __forceinline__ bf16x8 build_frag(u32 lo0, u32 lo1, u32 hi0, u32 hi1, int hd) {
    u32 sl0 = __shfl_xor(lo0, 32);
    u32 sh0 = __shfl_xor(hi0, 32);
    u32 sl1 = __shfl_xor(lo1, 32);
    u32 sh1 = __shfl_xor(hi1, 32);
    u32 w0 = hd ? sh0 : lo0;
    u32 w1 = hd ? sh1 : lo1;
    u32 w2 = hd ? hi0 : sl0;
    u32 w3 = hd ? hi1 : sl1;
    uint4 u = {w0, w1, w2, w3};
    return __builtin_bit_cast(bf16x8, u);
}

// Build both 16-k chunks of fragments from one 32x32 D accumulator
__device__ __forceinline__ void frags_from_D(const f32x16& d, int hd, bf16x8 fr[2]) {
    u32 pk[4][2];
    #pragma unroll
    for (int m = 0; m < 4; ++m) {
        pk[m][0] = pkbf(d[4*m+0], d[4*m+1]);
        pk[m][1] = pkbf(d[4*m+2], d[4*m+3]);
    }
    #pragma unroll
    for (int c2 = 0; c2 < 2; ++c2)
        fr[c2] = build_frag(pk[2*c2][0], pk[2*c2][1], pk[2*c2+1][0], pk[2*c2+1][1], hd);
}

// Weights fp32 -> bf16, transposed: ws = Wqkv_t[384][128] then Wproj_t[128][128]
__global__ void prep_weights_kernel(const float* __restrict__ wqkv,
                                    const float* __restrict__ wproj,
                                    bf16* __restrict__ ws) {
    int i = blockIdx.x * 256 + threadIdx.x;
    if (i < 384 * 128) {
        int n = i >> 7, k = i & 127;
        ws[i] = (bf16)wqkv[k * 384 + n];
    }
    if (i < 128 * 128) {
        int n = i >> 7, k = i & 127;
        ws[384 * 128 + i] = (bf16)wproj[k * 128 + n];
    }
}

// 4 waves/block, wave == head, full in-register dataflow (32x32x16 MFMA).
// LDS: only Xs [64 tok][128 ch] bf16 (16,384 B), 256B rows, byte^=((row&15)<<4).
//   Used as: X tile (staging->QKV inputs), then ALIAS O tile (attn out -> proj input).
// Q,K,V,P live entirely in registers via cvt_pk + shfl_xor(32) redistribution.
__launch_bounds__(256, 4)
__global__ void fused_window_attn(const float* __restrict__ x,
                                  const bf16* __restrict__ wqkv_t,
                                  const bf16* __restrict__ wproj_t,
                                  const float* __restrict__ bias,
                                  float* __restrict__ out) {
    __shared__ __align__(16) u16 Xs[64 * 128];

    const int tid  = threadIdx.x;
    const int blk  = blockIdx.x;
    const int h    = tid >> 6;    // wave == head
    const int lane = tid & 63;
    const int c    = lane & 31;   // D col / A-B row within 32-tile
    const int hd   = lane >> 5;   // half index (k-group)

    // ---------- stage x -> Xs (bf16, swizzled); zero pad rows 49..63 ----------
    const float* xw = x + (size_t)blk * (NTOK * CH);
    #pragma unroll
    for (int it = 0; it < 7; ++it) {
        int i = tid + it * 256;
        if (i < (NTOK * CH) / 4) {
            float4 v = reinterpret_cast<const float4*>(xw)[i];
            int e = i * 4, row = e >> 7, col = e & 127;
            bf16x4 pk4 = { (bf16)v.x, (bf16)v.y, (bf16)v.z, (bf16)v.w };
            *reinterpret_cast<bf16x4*>(reinterpret_cast<char*>(Xs)
                + row * 256 + ((col * 2) ^ ((row & 15) << 4))) = pk4;
        }
    }
    if (tid < 240) {  // rows 49..63 exact zeros (swizzle-invariant)
        uint4 zz = {0, 0, 0, 0};
        *reinterpret_cast<uint4*>(reinterpret_cast<char*>(Xs) + 49 * 256 + tid * 16) = zz;
    }
    __syncthreads();  // B1

    // fragment readers (Xs serves as A (rows=tok) and as B (X^T: k=ch, col=tok))
    auto xfrag = [&](int tt, int kc) -> bf16x8 {
        int row = tt * 32 + c;
        return *reinterpret_cast<const bf16x8*>(reinterpret_cast<const char*>(Xs)
            + row * 256 + ((kc * 32 + hd * 16) ^ ((row & 15) << 4)));
    };
    auto wfrag = [&](const bf16* wt, int nbase, int kc) -> bf16x8 {
        return *reinterpret_cast<const bf16x8*>(wt + (nbase + c) * 128 + kc * 16 + hd * 8);
    };

    // ---------- QK GEMM: D_q/D_k = mfma(A=W[32 dh], B=X^T) ----------
    f32x16 dq0 = zero16(), dq1 = zero16(), dk0 = zero16(), dk1 = zero16();
    #pragma unroll
    for (int kc = 0; kc < 8; ++kc) {
        bf16x8 x0 = xfrag(0, kc), x1 = xfrag(1, kc);
        bf16x8 wq = wfrag(wqkv_t, h * 32, kc);
        bf16x8 wk = wfrag(wqkv_t, 128 + h * 32, kc);
        dq0 = MFMA32(wq, x0, dq0);
        dq1 = MFMA32(wq, x1, dq1);
        dk0 = MFMA32(wk, x0, dk0);
        dk1 = MFMA32(wk, x1, dk1);
    }
    // redistribute to S-operand frags: qf[qt][c2] = Q^T[dh chunk][q], kf[st][c2] = K[s][dh chunk]
    bf16x8 qf[2][2], kf[2][2];
    frags_from_D(dq0, hd, qf[0]);
    frags_from_D(dq1, hd, qf[1]);
    frags_from_D(dk0, hd, kf[0]);
    frags_from_D(dk1, hd, kf[1]);

    // ---------- S^T = K @ Q^T : rows = s, cols = q ----------
    f32x16 sa[2][2];  // [st][qt]
    sa[0][0] = zero16(); sa[0][1] = zero16(); sa[1][0] = zero16(); sa[1][1] = zero16();
    #pragma unroll
    for (int st = 0; st < 2; ++st)
        #pragma unroll
        for (int qt = 0; qt < 2; ++qt)
            #pragma unroll
            for (int c2 = 0; c2 < 2; ++c2)
                sa[st][qt] = MFMA32(kf[st][c2], qf[qt][c2], sa[st][qt]);

    // ---------- softmax (per q = col = c, per-lane half + 1 shfl) + P frags ----------
    bf16x8 pf[4][2];  // [ks (s-chunk of 16)][qt]
    float rs[2];
    #pragma unroll
    for (int qt = 0; qt < 2; ++qt) {
        // mask pad s >= 49 in st=1 tile: s = 32 + 8m + rg + 4hd
        sa[1][qt][8] = hd ? -1e30f : sa[1][qt][8];   // s = 48 + 4hd
        #pragma unroll
        for (int r = 9; r < 16; ++r) sa[1][qt][r] = -1e30f;  // s >= 49 always
        float mx = -1e30f;
        #pragma unroll
        for (int r = 0; r < 16; ++r) mx = fmaxf(mx, fmaxf(sa[0][qt][r], sa[1][qt][r]));
        mx = fmaxf(mx, __shfl_xor(mx, 32));
        float l = 0.f;
        #pragma unroll
        for (int st = 0; st < 2; ++st)
            #pragma unroll
            for (int r = 0; r < 16; ++r) {
                float e = exp2f((sa[st][qt][r] - mx) * CEXP);
                sa[st][qt][r] = e;
                l += e;
            }
        l += __shfl_xor(l, 32);
        rs[qt] = 1.f / l;
        #pragma unroll
        for (int st = 0; st < 2; ++st) {
            bf16x8 t[2];
            frags_from_D(sa[st][qt], hd, t);  // P^T[s chunk][q]
            pf[st * 2 + 0][qt] = t[0];
            pf[st * 2 + 1][qt] = t[1];
        }
    }

    // ---------- V GEMM: D_v = mfma(A=X, B=Wv) : rows = tok(s), cols = dh ----------
    f32x16 dv0 = zero16(), dv1 = zero16();
    #pragma unroll
    for (int kc = 0; kc < 8; ++kc) {
        bf16x8 x0 = xfrag(0, kc), x1 = xfrag(1, kc);
        bf16x8 wv = wfrag(wqkv_t, 256 + h * 32, kc);
        dv0 = MFMA32(x0, wv, dv0);
        dv1 = MFMA32(x1, wv, dv1);
    }
    bf16x8 vfr[4];  // V^T[dh = c][s chunk ks]
    {
        bf16x8 t[2];
        frags_from_D(dv0, hd, t); vfr[0] = t[0]; vfr[1] = t[1];
        frags_from_D(dv1, hd, t); vfr[2] = t[0]; vfr[3] = t[1];
    }

    // ---------- O^T = V^T @ P^T : rows = dh, cols = q ----------
    f32x16 oo0 = zero16(), oo1 = zero16();
    #pragma unroll
    for (int ks = 0; ks < 4; ++ks) {
        oo0 = MFMA32(vfr[ks], pf[ks][0], oo0);
        oo1 = MFMA32(vfr[ks], pf[ks][1], oo1);
    }
    __syncthreads();  // B2: all waves done reading Xs (V pass was last use)

    // O -> Xs [tok=q][ch], packed b64, rescaled by 1/rowsum
    #pragma unroll
    for (int qt = 0; qt < 2; ++qt) {
        const f32x16& oq = qt ? oo1 : oo0;
        int q = qt * 32 + c;
        float scl = rs[qt];
        #pragma unroll
        for (int m = 0; m < 4; ++m) {
            bf16x4 pv4 = { (bf16)(oq[4*m+0] * scl), (bf16)(oq[4*m+1] * scl),
                           (bf16)(oq[4*m+2] * scl), (bf16)(oq[4*m+3] * scl) };
            *reinterpret_cast<bf16x4*>(reinterpret_cast<char*>(Xs)
                + q * 256 + ((h * 64 + m * 16 + hd * 8) ^ ((q & 15) << 4))) = pv4;
        }
    }
    __syncthreads();  // B3

    // ---------- proj: D = mfma(A=Wp[32 oc], B=O^T) + bias -> float4 out ----------
    f32x16 dp0 = zero16(), dp1 = zero16();
    #pragma unroll
    for (int kc = 0; kc < 8; ++kc) {
        bf16x8 o0 = xfrag(0, kc), o1 = xfrag(1, kc);
        bf16x8 wp = wfrag(wproj_t, h * 32, kc);
        dp0 = MFMA32(wp, o0, dp0);
        dp1 = MFMA32(wp, o1, dp1);
    }
    #pragma unroll
    for (int m = 0; m < 4; ++m) {
        int oc = h * 32 + 8 * m + 4 * hd;
        float4 bv = *reinterpret_cast<const float4*>(bias + oc);
        {   // tt = 0: tok = c < 32 < 49 always valid
            int tok = c;
            float4 r0 = { dp0[4*m+0] + bv.x, dp0[4*m+1] + bv.y,
                          dp0[4*m+2] + bv.z, dp0[4*m+3] + bv.w };
            *reinterpret_cast<float4*>(out + ((size_t)blk * NTOK + tok) * CH + oc) = r0;
        }
        if (c < 17) {  // tt = 1: tok = 32 + c < 49
            int tok = 32 + c;
            float4 r1 = { dp1[4*m+0] + bv.x, dp1[4*m+1] + bv.y,
                          dp1[4*m+2] + bv.z, dp1[4*m+3] + bv.w };
            *reinterpret_cast<float4*>(out + ((size_t)blk * NTOK + tok) * CH + oc) = r1;
        }
    }
}

extern "C" void kernel_launch(void* const* d_in, const int* in_sizes, int n_in,
                              void* d_out, int out_size, void* d_ws, size_t ws_size,
                              hipStream_t stream) {
    const float* x     = (const float*)d_in[0];
    const float* wqkv  = (const float*)d_in[1];
    const float* wproj = (const float*)d_in[2];
    const float* bias  = (const float*)d_in[3];
    float* out = (float*)d_out;
    bf16* ws   = (bf16*)d_ws;

    constexpr size_t WS_NEED = (size_t)(384 * 128 + 128 * 128) * sizeof(u16);
    if (ws_size < WS_NEED) return;

    prep_weights_kernel<<<192, 256, 0, stream>>>(wqkv, wproj, ws);
    fused_window_attn<<<4096, 256, 0, stream>>>(x, ws, ws + 384 * 128, bias, out);
}

// Round 6
// 103.618 us; speedup vs baseline: 1.4618x; 1.4618x over previous
//
#include <hip/hip_runtime.h>
#include <hip/hip_bf16.h>

typedef unsigned short u16;
typedef unsigned int u32;
typedef __bf16 bf16;
typedef __attribute__((ext_vector_type(8))) __bf16 bf16x8;
typedef __attribute__((ext_vector_type(4))) __bf16 bf16x4;
typedef __attribute__((ext_vector_type(16))) float f32x16;

#define MFMA32(A,B,C) __builtin_amdgcn_mfma_f32_32x32x16_bf16(A,B,C,0,0,0)

constexpr int NTOK = 49;
constexpr int CH   = 128;
// softmax scale folded into exp2: SCALE * log2(e)
constexpr float CEXP = 0.17677669529663687f * 1.4426950408889634f;

__device__ __forceinline__ f32x16 zero16() {
    f32x16 z = {0.f,0.f,0.f,0.f,0.f,0.f,0.f,0.f,0.f,0.f,0.f,0.f,0.f,0.f,0.f,0.f};
    return z;
}

__device__ __forceinline__ u32 pkbf(float a, float b) {
    u16 lo = __builtin_bit_cast(u16, (bf16)a);
    u16 hi = __builtin_bit_cast(u16, (bf16)b);
    return (u32)lo | ((u32)hi << 16);
}

// Cross-half exchange: D-layout (row=(reg&3)+8*(reg>>2)+4*hd) -> A/B-frag layout
// (k = c2*16 + hd*8 + j). For frag chunk c2: lo = pk[2*c2][j] (m=2c2), hi = pk[2c2+1][j].
__device__ __forceinline__ bf16x8 build_frag(u32 lo0, u32 lo1, u32 hi0, u32 hi1, int hd) {
    u32 sl0 = __shfl_xor(lo0, 32);
    u32 sh0 = __shfl_xor(hi0, 32);
    u32 sl1 = __shfl_xor(lo1, 32);
    u32 sh1 = __shfl_xor(hi1, 32);
    u32 w0 = hd ? sh0 : lo0;
    u32 w1 = hd ? sh1 : lo1;
    u32 w2 = hd ? hi0 : sl0;
    u32 w3 = hd ? hi1 : sl1;
    uint4 u = {w0, w1, w2, w3};
    return __builtin_bit_cast(bf16x8, u);
}

// Build both 16-k chunks of fragments from one 32x32 D accumulator
__device__ __forceinline__ void frags_from_D(const f32x16& d, int hd, bf16x8 fr[2]) {
    u32 pk[4][2];
    #pragma unroll
    for (int m = 0; m < 4; ++m) {
        pk[m][0] = pkbf(d[4*m+0], d[4*m+1]);
        pk[m][1] = pkbf(d[4*m+2], d[4*m+3]);
    }
    #pragma unroll
    for (int c2 = 0; c2 < 2; ++c2)
        fr[c2] = build_frag(pk[2*c2][0], pk[2*c2][1], pk[2*c2+1][0], pk[2*c2+1][1], hd);
}

// Weights fp32 -> bf16, transposed: ws = Wqkv_t[384][128] then Wproj_t[128][128]
__global__ void prep_weights_kernel(const float* __restrict__ wqkv,
                                    const float* __restrict__ wproj,
                                    bf16* __restrict__ ws) {
    int i = blockIdx.x * 256 + threadIdx.x;
    if (i < 384 * 128) {
        int n = i >> 7, k = i & 127;
        ws[i] = (bf16)wqkv[k * 384 + n];
    }
    if (i < 128 * 128) {
        int n = i >> 7, k = i & 127;
        ws[384 * 128 + i] = (bf16)wproj[k * 128 + n];
    }
}

// 4 waves/block, wave == head, full in-register dataflow (32x32x16 MFMA).
// LDS: only Xs [64 tok][128 ch] bf16 (16,384 B), 256B rows, byte^=((row&15)<<4).
// launch_bounds(256,3): ~170-reg budget -> NO SPILL (round-5 lesson: (256,4)'s
// 128-reg cap spilled accumulators to scratch, +170 MB of HBM traffic).
__launch_bounds__(256, 3)
__global__ void fused_window_attn(const float* __restrict__ x,
                                  const bf16* __restrict__ wqkv_t,
                                  const bf16* __restrict__ wproj_t,
                                  const float* __restrict__ bias,
                                  float* __restrict__ out) {
    __shared__ __align__(16) u16 Xs[64 * 128];

    const int tid  = threadIdx.x;
    const int blk  = blockIdx.x;
    const int h    = tid >> 6;    // wave == head
    const int lane = tid & 63;
    const int c    = lane & 31;   // D col / A-B row within 32-tile
    const int hd   = lane >> 5;   // half index (k-group)

    // ---------- stage x -> Xs (bf16, swizzled); zero pad rows 49..63 ----------
    const float* xw = x + (size_t)blk * (NTOK * CH);
    #pragma unroll
    for (int it = 0; it < 7; ++it) {
        int i = tid + it * 256;
        if (i < (NTOK * CH) / 4) {
            float4 v = reinterpret_cast<const float4*>(xw)[i];
            int e = i * 4, row = e >> 7, col = e & 127;
            bf16x4 pk4 = { (bf16)v.x, (bf16)v.y, (bf16)v.z, (bf16)v.w };
            *reinterpret_cast<bf16x4*>(reinterpret_cast<char*>(Xs)
                + row * 256 + ((col * 2) ^ ((row & 15) << 4))) = pk4;
        }
    }
    if (tid < 240) {  // rows 49..63 exact zeros (swizzle-invariant)
        uint4 zz = {0, 0, 0, 0};
        *reinterpret_cast<uint4*>(reinterpret_cast<char*>(Xs) + 49 * 256 + tid * 16) = zz;
    }
    __syncthreads();  // B1

    // fragment readers (Xs serves as A (rows=tok) and as B (X^T: k=ch, col=tok))
    auto xfrag = [&](int tt, int kc) -> bf16x8 {
        int row = tt * 32 + c;
        return *reinterpret_cast<const bf16x8*>(reinterpret_cast<const char*>(Xs)
            + row * 256 + ((kc * 32 + hd * 16) ^ ((row & 15) << 4)));
    };
    auto wfrag = [&](const bf16* wt, int nbase, int kc) -> bf16x8 {
        return *reinterpret_cast<const bf16x8*>(wt + (nbase + c) * 128 + kc * 16 + hd * 8);
    };

    // ---------- QK GEMM: D_q/D_k = mfma(A=W[32 dh], B=X^T) ----------
    bf16x8 qf[2][2], kf[2][2];
    {
        f32x16 dq0 = zero16(), dq1 = zero16(), dk0 = zero16(), dk1 = zero16();
        #pragma unroll
        for (int kc = 0; kc < 8; ++kc) {
            bf16x8 x0 = xfrag(0, kc), x1 = xfrag(1, kc);
            bf16x8 wq = wfrag(wqkv_t, h * 32, kc);
            bf16x8 wk = wfrag(wqkv_t, 128 + h * 32, kc);
            dq0 = MFMA32(wq, x0, dq0);
            dq1 = MFMA32(wq, x1, dq1);
            dk0 = MFMA32(wk, x0, dk0);
            dk1 = MFMA32(wk, x1, dk1);
        }
        frags_from_D(dq0, hd, qf[0]);
        frags_from_D(dq1, hd, qf[1]);
        frags_from_D(dk0, hd, kf[0]);
        frags_from_D(dk1, hd, kf[1]);
    }

    // ---------- V GEMM (hoisted: finish all Xs reads early, overlap with softmax) ----------
    bf16x8 vfr[4];  // V^T[dh = c][s chunk ks]
    {
        f32x16 dv0 = zero16(), dv1 = zero16();
        #pragma unroll
        for (int kc = 0; kc < 8; ++kc) {
            bf16x8 x0 = xfrag(0, kc), x1 = xfrag(1, kc);
            bf16x8 wv = wfrag(wqkv_t, 256 + h * 32, kc);
            dv0 = MFMA32(x0, wv, dv0);
            dv1 = MFMA32(x1, wv, dv1);
        }
        bf16x8 t[2];
        frags_from_D(dv0, hd, t); vfr[0] = t[0]; vfr[1] = t[1];
        frags_from_D(dv1, hd, t); vfr[2] = t[0]; vfr[3] = t[1];
    }
    __syncthreads();  // B2: all Xs reads complete; O may clobber Xs after PV

    // ---------- per-qt: S^T = K @ Q^T, softmax, P frags (32 regs of S live at a time) ----------
    bf16x8 pf[4][2];  // [s-chunk of 16][qt]
    float rs[2];
    #pragma unroll
    for (int qt = 0; qt < 2; ++qt) {
        f32x16 s0 = zero16(), s1 = zero16();
        #pragma unroll
        for (int c2 = 0; c2 < 2; ++c2) {
            s0 = MFMA32(kf[0][c2], qf[qt][c2], s0);
            s1 = MFMA32(kf[1][c2], qf[qt][c2], s1);
        }
        // mask pad s >= 49 in st=1 tile: s = 32 + 8m + rg + 4hd
        s1[8] = hd ? -1e30f : s1[8];   // s = 48 + 4hd
        #pragma unroll
        for (int r = 9; r < 16; ++r) s1[r] = -1e30f;
        float mx = -1e30f;
        #pragma unroll
        for (int r = 0; r < 16; ++r) mx = fmaxf(mx, fmaxf(s0[r], s1[r]));
        mx = fmaxf(mx, __shfl_xor(mx, 32));
        float l = 0.f;
        #pragma unroll
        for (int r = 0; r < 16; ++r) {
            float e0 = exp2f((s0[r] - mx) * CEXP);
            float e1 = exp2f((s1[r] - mx) * CEXP);
            s0[r] = e0; s1[r] = e1;
            l += e0 + e1;
        }
        l += __shfl_xor(l, 32);
        rs[qt] = 1.f / l;
        bf16x8 t[2];
        frags_from_D(s0, hd, t); pf[0][qt] = t[0]; pf[1][qt] = t[1];
        frags_from_D(s1, hd, t); pf[2][qt] = t[0]; pf[3][qt] = t[1];
    }

    // ---------- O^T = V^T @ P^T : rows = dh, cols = q ----------
    f32x16 oo0 = zero16(), oo1 = zero16();
    #pragma unroll
    for (int ks = 0; ks < 4; ++ks) {
        oo0 = MFMA32(vfr[ks], pf[ks][0], oo0);
        oo1 = MFMA32(vfr[ks], pf[ks][1], oo1);
    }

    // O -> Xs [tok=q][ch], packed b64, rescaled by 1/rowsum
    #pragma unroll
    for (int qt = 0; qt < 2; ++qt) {
        const f32x16& oq = qt ? oo1 : oo0;
        int q = qt * 32 + c;
        float scl = rs[qt];
        #pragma unroll
        for (int m = 0; m < 4; ++m) {
            bf16x4 pv4 = { (bf16)(oq[4*m+0] * scl), (bf16)(oq[4*m+1] * scl),
                           (bf16)(oq[4*m+2] * scl), (bf16)(oq[4*m+3] * scl) };
            *reinterpret_cast<bf16x4*>(reinterpret_cast<char*>(Xs)
                + q * 256 + ((h * 64 + m * 16 + hd * 8) ^ ((q & 15) << 4))) = pv4;
        }
    }
    __syncthreads();  // B3

    // ---------- proj: D = mfma(A=Wp[32 oc], B=O^T) + bias -> float4 out ----------
    f32x16 dp0 = zero16(), dp1 = zero16();
    #pragma unroll
    for (int kc = 0; kc < 8; ++kc) {
        bf16x8 o0 = xfrag(0, kc), o1 = xfrag(1, kc);
        bf16x8 wp = wfrag(wproj_t, h * 32, kc);
        dp0 = MFMA32(wp, o0, dp0);
        dp1 = MFMA32(wp, o1, dp1);
    }
    #pragma unroll
    for (int m = 0; m < 4; ++m) {
        int oc = h * 32 + 8 * m + 4 * hd;
        float4 bv = *reinterpret_cast<const float4*>(bias + oc);
        {   // tt = 0: tok = c < 32 < 49 always valid
            int tok = c;
            float4 r0 = { dp0[4*m+0] + bv.x, dp0[4*m+1] + bv.y,
                          dp0[4*m+2] + bv.z, dp0[4*m+3] + bv.w };
            *reinterpret_cast<float4*>(out + ((size_t)blk * NTOK + tok) * CH + oc) = r0;
        }
        if (c < 17) {  // tt = 1: tok = 32 + c < 49
            int tok = 32 + c;
            float4 r1 = { dp1[4*m+0] + bv.x, dp1[4*m+1] + bv.y,
                          dp1[4*m+2] + bv.z, dp1[4*m+3] + bv.w };
            *reinterpret_cast<float4*>(out + ((size_t)blk * NTOK + tok) * CH + oc) = r1;
        }
    }
}

extern "C" void kernel_launch(void* const* d_in, const int* in_sizes, int n_in,
                              void* d_out, int out_size, void* d_ws, size_t ws_size,
                              hipStream_t stream) {
    const float* x     = (const float*)d_in[0];
    const float* wqkv  = (const float*)d_in[1];
    const float* wproj = (const float*)d_in[2];
    const float* bias  = (const float*)d_in[3];
    float* out = (float*)d_out;
    bf16* ws   = (bf16*)d_ws;

    constexpr size_t WS_NEED = (size_t)(384 * 128 + 128 * 128) * sizeof(u16);
    if (ws_size < WS_NEED) return;

    prep_weights_kernel<<<192, 256, 0, stream>>>(wqkv, wproj, ws);
    fused_window_attn<<<4096, 256, 0, stream>>>(x, ws, ws + 384 * 128, bias, out);
}